// Round 3
// baseline (428.004 us; speedup 1.0000x reference)
//
#include <hip/hip_runtime.h>
#include <cstdint>
#include <cstddef>

#define TAU_D 2.053748910631823
#define M_DIM 8192
#define N_DIM 4096
#define K_DIM 4096

typedef float f32x4 __attribute__((ext_vector_type(4)));
typedef short bf16x8 __attribute__((ext_vector_type(8)));

typedef __attribute__((address_space(1))) void gvoid_t;
typedef __attribute__((address_space(3))) void lvoid_t;

__device__ __forceinline__ void gload_lds16(const void* g, void* l) {
    __builtin_amdgcn_global_load_lds((const gvoid_t*)g, (lvoid_t*)l, 16, 0, 0);
}

__device__ __forceinline__ unsigned int pack2bf(float lo, float hi) {
    unsigned int ul = __float_as_uint(lo);
    unsigned int uh = __float_as_uint(hi);
    ul = (ul + 0x7FFFu + ((ul >> 16) & 1u)) >> 16;
    uh = (uh + 0x7FFFu + ((uh >> 16) & 1u)) >> 16;
    return ul | (uh << 16);
}

// fp32 -> bf16 (RNE), vectorized: 16B in / 8B out per thread per iter.
__global__ void cvt_f32_to_bf16(const float4* __restrict__ in,
                                uint2* __restrict__ out, int n4) {
    int i = blockIdx.x * blockDim.x + threadIdx.x;
    const int stride = gridDim.x * blockDim.x;
    for (; i < n4; i += stride) {
        float4 a = in[i];
        uint2 o;
        o.x = pack2bf(a.x, a.y);
        o.y = pack2bf(a.z, a.w);
        out[i] = o;
    }
}

// C = x @ W^T + bias, masked by tstat(x0,w0) < TAU -> 0.
// 128x128 tile, BK=32, 4 waves (2x2), 16x16x32 bf16 MFMA, 4x4 frags/wave.
// Mask replicates numpy/BLAS fp32 sgemm semantics exactly:
//   y1 = sequential fma chain over k ascending
//   s2 = sequential fma chain of fl(x^2)*fl(w^2)
//   t  = |y1| / sqrtf(s2/16), IEEE sqrt/div, compare vs (float)TAU.
template<int SM>
__global__ __launch_bounds__(256, 2) void gemm_masked(
    const unsigned short* __restrict__ Ab,   // x bf16 [M][K]
    const unsigned short* __restrict__ Bb,   // W bf16 [N][K]
    const float* __restrict__ X,             // x fp32 (mask + fallback staging)
    const float* __restrict__ Wt,            // W fp32
    const float* __restrict__ bias,
    float* __restrict__ out)
{
    __shared__ __align__(16) unsigned short As[128 * 32];
    __shared__ __align__(16) unsigned short Bs[128 * 32];

    const int tid  = threadIdx.x;
    const int wave = tid >> 6;
    const int lane = tid & 63;
    const int rowBase = blockIdx.y * 128;
    const int colBase = blockIdx.x * 128;
    const int wr = wave >> 1;   // wave row (0..1) -> 64 rows each
    const int wc = wave & 1;    // wave col (0..1) -> 64 cols each
    const int lr = lane & 15;
    const int lq = lane >> 4;

    f32x4 acc[4][4];
    #pragma unroll
    for (int m = 0; m < 4; ++m)
        #pragma unroll
        for (int n = 0; n < 4; ++n)
            acc[m][n] = (f32x4){0.f, 0.f, 0.f, 0.f};

    // Staging geometry: flat LDS byte = tid*16 + issue*4096
    //  -> row = tid/4 + issue*64, col(bf16) = (tid&3)*8, 32 cols/row.
    const int srow = tid >> 2;
    const int scol = (tid & 3) * 8;
    char* asdst = (char*)As + wave * 1024;   // wave-uniform; HW adds lane*16
    char* bsdst = (char*)Bs + wave * 1024;

    const unsigned short* aptr = Ab + (size_t)(rowBase + srow) * K_DIM + scol;
    const unsigned short* bptr = Bb + (size_t)(colBase + srow) * K_DIM + scol;
    const float* afp = X  + (size_t)(rowBase + srow) * K_DIM + scol;
    const float* bfp = Wt + (size_t)(colBase + srow) * K_DIM + scol;

    for (int kt = 0; kt < K_DIM; kt += 32) {
        if constexpr (SM == 0) {
            gload_lds16(aptr,                    asdst);
            gload_lds16(aptr + 64 * K_DIM,       asdst + 4096);
            gload_lds16(bptr,                    bsdst);
            gload_lds16(bptr + 64 * K_DIM,       bsdst + 4096);
            aptr += 32; bptr += 32;
        } else {
            #pragma unroll
            for (int issue = 0; issue < 2; ++issue) {
                const float* sa = afp + (size_t)issue * 64 * K_DIM;
                const float* sb = bfp + (size_t)issue * 64 * K_DIM;
                float4 a0 = *(const float4*)(sa);
                float4 a1 = *(const float4*)(sa + 4);
                float4 b0 = *(const float4*)(sb);
                float4 b1 = *(const float4*)(sb + 4);
                uint4 pa, pb;
                pa.x = pack2bf(a0.x, a0.y); pa.y = pack2bf(a0.z, a0.w);
                pa.z = pack2bf(a1.x, a1.y); pa.w = pack2bf(a1.z, a1.w);
                pb.x = pack2bf(b0.x, b0.y); pb.y = pack2bf(b0.z, b0.w);
                pb.z = pack2bf(b1.x, b1.y); pb.w = pack2bf(b1.z, b1.w);
                *(uint4*)((char*)As + issue * 4096 + tid * 16) = pa;
                *(uint4*)((char*)Bs + issue * 4096 + tid * 16) = pb;
            }
            afp += 32; bfp += 32;
        }
        __syncthreads();

        bf16x8 af[4], bq[4];
        #pragma unroll
        for (int m = 0; m < 4; ++m)
            af[m] = *(const bf16x8*)(As + (wr * 64 + m * 16 + lr) * 32 + lq * 8);
        #pragma unroll
        for (int n = 0; n < 4; ++n)
            bq[n] = *(const bf16x8*)(Bs + (wc * 64 + n * 16 + lr) * 32 + lq * 8);
        #pragma unroll
        for (int m = 0; m < 4; ++m)
            #pragma unroll
            for (int n = 0; n < 4; ++n)
                acc[m][n] = __builtin_amdgcn_mfma_f32_16x16x32_bf16(
                    af[m], bq[n], acc[m][n], 0, 0, 0);
        __syncthreads();
    }

    // ---- Epilogue: mask from fp32 x[:, :16], W[:, :16]; add bias; store ----
    // Reuse LDS: x0s = 128x16 f32 (8KB), w0s = 128x16 f32 (8KB).
    float* x0s = (float*)As;
    float* w0s = (float*)Bs;
    #pragma unroll
    for (int i = 0; i < 2; ++i) {
        int idx = tid + i * 256;           // 0..511 float4 slots
        int r = idx >> 2, q = (idx & 3) * 4;
        *(float4*)(x0s + r * 16 + q) =
            *(const float4*)(X + (size_t)(rowBase + r) * K_DIM + q);
        *(float4*)(w0s + r * 16 + q) =
            *(const float4*)(Wt + (size_t)(colBase + r) * K_DIM + q);
    }
    __syncthreads();

    const float TAU32 = (float)TAU_D;   // numpy weak-scalar f64->f32 cast

    float wv[4][16];
    float bv[4];
    #pragma unroll
    for (int n = 0; n < 4; ++n) {
        int c = wc * 64 + n * 16 + lr;
        #pragma unroll
        for (int q = 0; q < 4; ++q)
            *(f32x4*)&wv[n][q * 4] = *(const f32x4*)(w0s + c * 16 + q * 4);
        bv[n] = bias[colBase + c];
    }

    #pragma unroll
    for (int m = 0; m < 4; ++m) {
        #pragma unroll
        for (int j = 0; j < 4; ++j) {
            const int r = wr * 64 + m * 16 + lq * 4 + j;
            float xv[16];
            #pragma unroll
            for (int q = 0; q < 4; ++q)
                *(f32x4*)&xv[q * 4] = *(const f32x4*)(x0s + r * 16 + q * 4);
            const size_t orow = (size_t)(rowBase + r) * N_DIM + colBase;
            #pragma unroll
            for (int n = 0; n < 4; ++n) {
                // Replicate BLAS sgemm: single-accumulator fma chain, k ascending.
                float y1 = 0.f, s2 = 0.f;
                #pragma unroll
                for (int k = 0; k < 16; ++k) {
                    float xk = xv[k];
                    float wk = wv[n][k];
                    float xx = xk * xk;   // fl(x^2)  (ref squares before matmul)
                    float ww = wk * wk;   // fl(w^2)
                    y1 = fmaf(xk, wk, y1);
                    s2 = fmaf(xx, ww, s2);
                }
                float t = fabsf(y1) / sqrtf(s2 * 0.0625f);   // s2/16 exact
                bool pass = (t < TAU32);
                float v = pass ? 0.0f : (acc[m][n][j] + bv[n]);
                out[orow + wc * 64 + n * 16 + lr] = v;
            }
        }
    }
}

extern "C" void kernel_launch(void* const* d_in, const int* in_sizes, int n_in,
                              void* d_out, int out_size, void* d_ws, size_t ws_size,
                              hipStream_t stream) {
    const float* x    = (const float*)d_in[0];
    const float* W    = (const float*)d_in[1];
    const float* bias = (const float*)d_in[2];
    float* out = (float*)d_out;

    const size_t needA = (size_t)M_DIM * K_DIM * 2;   // 64 MB
    const size_t needB = (size_t)N_DIM * K_DIM * 2;   // 32 MB
    dim3 grid(N_DIM / 128, M_DIM / 128);              // 32 x 64

    if (ws_size >= needA + needB) {
        unsigned short* xb = (unsigned short*)d_ws;
        unsigned short* wb = (unsigned short*)((char*)d_ws + needA);
        cvt_f32_to_bf16<<<2048, 256, 0, stream>>>(
            (const float4*)x, (uint2*)xb, (M_DIM * K_DIM) / 4);
        cvt_f32_to_bf16<<<2048, 256, 0, stream>>>(
            (const float4*)W, (uint2*)wb, (N_DIM * K_DIM) / 4);
        gemm_masked<0><<<grid, 256, 0, stream>>>(xb, wb, x, W, bias, out);
    } else {
        gemm_masked<1><<<grid, 256, 0, stream>>>(nullptr, nullptr, x, W, bias, out);
    }
}